// Round 2
// baseline (11522.389 us; speedup 1.0000x reference)
//
#include <hip/hip_runtime.h>

// LSTM: SEQ=256, INPUT_DIM=1, HIDDEN=1024, NUM_CLASSES=10, BATCH=512, fp32 in/out.
// Persistent kernel, 256 wgs x 256 threads (1 wg/CU by construction: ~370 VGPR -> 1 wave/SIMD).
// wg (r,c): h-slice [32r,32r+32), batch-slice [64c,64c+64). Wave w owns h-sub [32r+8w,+8);
// one 32x32x16 MFMA tile packs all 4 gates (rows = gate*8+dh) -> gates co-located per lane.
// ht is stored in global pre-packed in MFMA B-fragment order so staging is linear global_load_lds.

#define HID  1024
#define SEQL 256

typedef __bf16 bf16x8 __attribute__((ext_vector_type(8)));
typedef float  f32x16 __attribute__((ext_vector_type(16)));

#define AS1 __attribute__((address_space(1)))
#define AS3 __attribute__((address_space(3)))

__device__ __forceinline__ float fast_sigmoid(float v) {
    float e = __expf(-v);
    return 1.0f / (1.0f + e);
}
__device__ __forceinline__ float fast_tanh(float v) {
    float e = __expf(2.0f * v);          // saturates correctly at +/-inf
    return 1.0f - 2.0f / (e + 1.0f);
}
__device__ __forceinline__ unsigned pk2bf(float a, float b) {
    unsigned short ua = __builtin_bit_cast(unsigned short, (__bf16)a);
    unsigned short ub = __builtin_bit_cast(unsigned short, (__bf16)b);
    return (unsigned)ua | ((unsigned)ub << 16);
}
__device__ __forceinline__ float bfhi(unsigned u) {        // high bf16 of a packed word
    return __builtin_bit_cast(float, u & 0xFFFF0000u);
}
__device__ __forceinline__ float bflo(unsigned u) {        // low bf16 of a packed word
    return __builtin_bit_cast(float, u << 16);
}

__global__ __launch_bounds__(256) void lstm_init(unsigned short* htA, unsigned* cnt, float* out) {
    int idx = blockIdx.x * 256 + threadIdx.x;          // 65536 threads
    uint4 z; z.x = 0; z.y = 0; z.z = 0; z.w = 0;
    ((uint4*)htA)[idx] = z;                            // zero 1 MB (ht(-1) = 0, frag order)
    if (idx < 512) cnt[idx] = 0;                       // 8 group counters (64-uint stride)
    if (idx < 5120) out[idx] = 0.05f;                  // diagnostic sentinel, overwritten by lstm_main
}

__global__ __attribute__((amdgpu_flat_work_group_size(256, 256), amdgpu_waves_per_eu(1, 1)))
void lstm_main(
    const float* __restrict__ x,
    const float* __restrict__ Wgx, const float* __restrict__ Wgh, const float* __restrict__ bg,
    const float* __restrict__ Wix, const float* __restrict__ Wih, const float* __restrict__ bi,
    const float* __restrict__ Wfx, const float* __restrict__ Wfh, const float* __restrict__ bf_,
    const float* __restrict__ Wox, const float* __restrict__ Woh, const float* __restrict__ bo,
    const float* __restrict__ Wph, const float* __restrict__ bp,
    float* __restrict__ out,
    unsigned short* __restrict__ htA, unsigned short* __restrict__ htB,
    unsigned* __restrict__ cnt)
{
    // B-fragment staging: [buf][kk_local(16)][nt(2)][lane(64)] of 16B -> 64 KiB
    __shared__ uint4 ldsB[2][16][2][64];

    const int tid = threadIdx.x;
    const int w   = tid >> 6;        // wave 0..3
    const int l   = tid & 63;
    const int l31 = l & 31;
    const int h5  = l >> 5;
    const int gid = blockIdx.x;
    const int c   = gid & 7;         // batch group (64 batches) — XCD-aligned
    const int r   = gid >> 3;        // h group (32 h)

    // ---- load A fragments (weights, bf16) into registers: 64 k-steps x bf16x8 = 256 VGPR ----
    // A row m = l31: gate = m>>3, dh = m&7 ; within one MFMA, k = h5*8 + e
    const int gate = l31 >> 3;
    const int hrow = (r << 5) + (w << 3) + (l & 7);
    const float* Wsel = (gate == 0) ? Wgh : (gate == 1) ? Wih : (gate == 2) ? Wfh : Woh;
    const float* wrow = Wsel + hrow * HID + (h5 << 3);
    bf16x8 A[64];
#pragma unroll
    for (int kk = 0; kk < 64; ++kk) {
        const float4* p = (const float4*)(wrow + kk * 16);
        float4 u0 = p[0], u1 = p[1];
        bf16x8 a;
        a[0] = (__bf16)u0.x; a[1] = (__bf16)u0.y; a[2] = (__bf16)u0.z; a[3] = (__bf16)u0.w;
        a[4] = (__bf16)u1.x; a[5] = (__bf16)u1.y; a[6] = (__bf16)u1.z; a[7] = (__bf16)u1.w;
        A[kk] = a;
        __builtin_amdgcn_sched_barrier(0);   // bound register pressure during init
    }

    // ---- per-lane Wx / bias for the 16 accumulator rows ----
    // acc reg j -> D row = (j&3) + 8*(j>>2) + 4*h5  => gate=j>>2, dh=(j&3)+4*h5
    float wx16[16], bs16[16];
    {
        const float* WxA[4] = {Wgx, Wix, Wfx, Wox};
        const float* bA[4]  = {bg, bi, bf_, bo};
#pragma unroll
        for (int j = 0; j < 16; ++j) {
            int g = j >> 2;
            int h = (r << 5) + (w << 3) + (j & 3) + (h5 << 2);
            wx16[j] = WxA[g][h];
            bs16[j] = bA[g][h];
        }
    }

    float ct[8];
#pragma unroll
    for (int i = 0; i < 8; ++i) ct[i] = 0.f;

    const unsigned short* htR = htA;   // ht(t-1), fragment order
    unsigned short*       htW = htB;   // ht(t)
    unsigned* mycnt = cnt + (c << 6);

    for (int t = 0; t < SEQL; ++t) {
        // per-step input values (b = 64c + nt*32 + l31)
        float xv0 = x[(unsigned)((c << 6) + l31) * SEQL + (unsigned)t];
        float xv1 = x[(unsigned)((c << 6) + 32 + l31) * SEQL + (unsigned)t];

        const unsigned short* gR = htR + (c << 16);   // this group's 128 KiB region

        // stage chunk 0 (each wave: 8 x global_load_lds of 1 KiB)
#pragma unroll
        for (int j = 0; j < 8; ++j) {
            int q = (w << 3) + j;                      // pair id = kk_local*2 + nt
            const void* g = (const void*)(gR + q * 512 + (l << 3));
            __builtin_amdgcn_global_load_lds((const AS1 void*)g,
                (AS3 void*)&ldsB[0][q >> 1][q & 1][0], 16, 0, 0);
        }

        // init accumulators with bias + Wx*x_t
        f32x16 acc0, acc1;
#pragma unroll
        for (int j = 0; j < 16; ++j) {
            acc0[j] = fmaf(wx16[j], xv0, bs16[j]);
            acc1[j] = fmaf(wx16[j], xv1, bs16[j]);
        }

        // ---- K loop: 4 chunks x 16 k-steps, double-buffered staging ----
#pragma unroll
        for (int ch = 0; ch < 4; ++ch) {
            if (ch < 3) {
#pragma unroll
                for (int j = 0; j < 8; ++j) {
                    int q = (w << 3) + j;
                    const void* g = (const void*)(gR + (ch + 1) * 16384 + q * 512 + (l << 3));
                    __builtin_amdgcn_global_load_lds((const AS1 void*)g,
                        (AS3 void*)&ldsB[(ch + 1) & 1][q >> 1][q & 1][0], 16, 0, 0);
                }
                // per-wave: ch+1's 8 loads may remain outstanding; ch's 8 are done
                asm volatile("s_waitcnt vmcnt(8)" ::: "memory");
            } else {
                asm volatile("s_waitcnt vmcnt(0)" ::: "memory");
            }
            __builtin_amdgcn_s_barrier();
            asm volatile("" ::: "memory");
#pragma unroll
            for (int kk = 0; kk < 16; ++kk) {
                bf16x8 b0 = __builtin_bit_cast(bf16x8, ldsB[ch & 1][kk][0][l]);
                bf16x8 b1 = __builtin_bit_cast(bf16x8, ldsB[ch & 1][kk][1][l]);
                acc0 = __builtin_amdgcn_mfma_f32_32x32x16_bf16(A[ch * 16 + kk], b0, acc0, 0, 0, 0);
                acc1 = __builtin_amdgcn_mfma_f32_32x32x16_bf16(A[ch * 16 + kk], b1, acc1, 0, 0, 0);
            }
            asm volatile("" ::: "memory");
            __builtin_amdgcn_s_barrier();
        }

        // ---- activations + state update (all 4 gates live in this lane) ----
        float htv[8];
#pragma unroll
        for (int nt = 0; nt < 2; ++nt) {
            f32x16 ac = nt ? acc1 : acc0;
#pragma unroll
            for (int d = 0; d < 4; ++d) {
                float g  = fast_tanh(ac[d]);
                float ii = fast_sigmoid(ac[4 + d]);
                float ff = fast_sigmoid(ac[8 + d]);
                float oo = fast_sigmoid(ac[12 + d]);
                float cc = fmaf(ct[nt * 4 + d], ff, g * ii);
                ct[nt * 4 + d] = cc;
                htv[nt * 4 + d] = fast_tanh(cc) * oo;
            }
        }

        // ---- store ht(t) as bf16 in B-fragment order ----
        {
            unsigned short* gW = htW + (c << 16);
            int kkw  = (r << 1) + (w >> 1);
            int slot = ((w & 1) << 5) + l31;
#pragma unroll
            for (int nt = 0; nt < 2; ++nt) {
                uint2 v;
                v.x = pk2bf(htv[nt * 4 + 0], htv[nt * 4 + 1]);
                v.y = pk2bf(htv[nt * 4 + 2], htv[nt * 4 + 3]);
                *(uint2*)(gW + (((kkw * 2 + nt) * 64 + slot) * 8 + (h5 << 2))) = v;
            }
        }

        // ---- group barrier (32 wgs sharing this batch group) ----
        __threadfence();                   // release ht stores (agent scope)
        __syncthreads();
        if (tid == 0) {
            __hip_atomic_fetch_add(mycnt, 1u, __ATOMIC_RELEASE, __HIP_MEMORY_SCOPE_AGENT);
            unsigned tgt = 32u * (unsigned)(t + 1);
            while (__hip_atomic_load(mycnt, __ATOMIC_ACQUIRE, __HIP_MEMORY_SCOPE_AGENT) < tgt) {
                __builtin_amdgcn_s_sleep(2);
            }
        }
        __syncthreads();
        __threadfence();                   // acquire: no stale L1 when reading others' ht

        const unsigned short* tmp = htR; htR = htW; htW = (unsigned short*)tmp;
    }

    // ---- final projection: out[b][cls] = Wph[cls,:] . ht[:,b] + bp[cls] ----
    // ht read straight from the bf16 fragment-order buffer (htR = final after last swap):
    //   elem(h, b) at region c*65536 + (h>>4)*1024 + ((b>>5)&1)*512 + ((h>>3)&1)*256 + (b&31)*8 + (h&7)
    // Lane l covers h in [16l, 16l+16): two uint4 at +0 and +256 elems (=32 uint4).
    {
        const unsigned short* hfin = htR + (c << 16);
        for (int p = w; p < 20; p += 4) {
            int bloc = (r << 1) + (p / 10);            // in-group batch 0..63
            int bb   = (c << 6) + bloc;
            int cls  = p % 10;
            const uint4* base = (const uint4*)(hfin + l * 1024 + ((bloc >> 5) & 1) * 512
                                                    + (bloc & 31) * 8);
            uint4 u0 = base[0];                        // h = 16l + 0..7
            uint4 u1 = base[32];                       // h = 16l + 8..15
            const float* wp = Wph + (unsigned)cls * HID + (unsigned)l * 16;
            float s = 0.f;
            const unsigned* pu0 = (const unsigned*)&u0;
            const unsigned* pu1 = (const unsigned*)&u1;
#pragma unroll
            for (int e = 0; e < 4; ++e) {
                s = fmaf(wp[2 * e],     bflo(pu0[e]), s);
                s = fmaf(wp[2 * e + 1], bfhi(pu0[e]), s);
                s = fmaf(wp[8 + 2 * e],     bflo(pu1[e]), s);
                s = fmaf(wp[8 + 2 * e + 1], bfhi(pu1[e]), s);
            }
#pragma unroll
            for (int off = 32; off > 0; off >>= 1) s += __shfl_xor(s, off, 64);
            if (l == 0) out[bb * 10 + cls] = s + bp[cls];
        }
    }
}

extern "C" void kernel_launch(void* const* d_in, const int* in_sizes, int n_in,
                              void* d_out, int out_size, void* d_ws, size_t ws_size,
                              hipStream_t stream) {
    const float* x   = (const float*)d_in[0];
    const float* Wgx = (const float*)d_in[1];
    const float* Wgh = (const float*)d_in[2];
    const float* bg  = (const float*)d_in[3];
    const float* Wix = (const float*)d_in[4];
    const float* Wih = (const float*)d_in[5];
    const float* bi  = (const float*)d_in[6];
    const float* Wfx = (const float*)d_in[7];
    const float* Wfh = (const float*)d_in[8];
    const float* bf_ = (const float*)d_in[9];
    const float* Wox = (const float*)d_in[10];
    const float* Woh = (const float*)d_in[11];
    const float* bo  = (const float*)d_in[12];
    const float* Wph = (const float*)d_in[13];
    const float* bp  = (const float*)d_in[14];
    float* out = (float*)d_out;

    char* ws = (char*)d_ws;
    unsigned short* htA = (unsigned short*)ws;                 // 1 MiB, ht buffer A (frag order)
    unsigned short* htB = (unsigned short*)(ws + (1 << 20));   // 1 MiB, ht buffer B
    unsigned*       cnt = (unsigned*)(ws + (2 << 20));         // 2 KiB, group counters

    lstm_init<<<dim3(256), dim3(256), 0, stream>>>(htA, cnt, out);

    lstm_main<<<dim3(256), dim3(256), 0, stream>>>(
        x, Wgx, Wgh, bg, Wix, Wih, bi, Wfx, Wfh, bf_,
        Wox, Woh, bo, Wph, bp, out, htA, htB, cnt);
}

// Round 3
// 2130.968 us; speedup vs baseline: 5.4071x; 5.4071x over previous
//
#include <hip/hip_runtime.h>

// LSTM: SEQ=256, INPUT_DIM=1, HIDDEN=1024, NUM_CLASSES=10, BATCH=512, fp32 in/out.
// Persistent kernel, 256 wgs x 256 threads, 1 wg/CU (waves_per_eu(1,1) => 4 waves/CU => forced).
// wg (r,c): h-slice [32r,32r+32), batch-slice [64c,64c+64). Wave w owns h-sub [32r+8w,+8);
// one 32x32x16 MFMA tile packs all 4 gates (rows = gate*8+dh) -> gates co-located per lane.
// ht lives in global in MFMA B-fragment order; cross-wg exchange uses DEVICE-SCOPE (sc1)
// stores/loads + a relaxed monotonic atomic counter per batch-group. NO __threadfence
// (its buffer_wbl2/buffer_inv full-L2 maintenance was the round-2 45us/step bottleneck).

#define HID  1024
#define SEQL 256

typedef __bf16 bf16x8 __attribute__((ext_vector_type(8)));
typedef float  f32x16 __attribute__((ext_vector_type(16)));
typedef unsigned u32x4 __attribute__((ext_vector_type(4)));

#define AS1 __attribute__((address_space(1)))
#define AS3 __attribute__((address_space(3)))

__device__ __forceinline__ float fast_sigmoid(float v) {
    float e = __expf(-v);
    return 1.0f / (1.0f + e);
}
__device__ __forceinline__ float fast_tanh(float v) {
    float e = __expf(2.0f * v);          // saturates correctly at +/-inf
    return 1.0f - 2.0f / (e + 1.0f);
}
__device__ __forceinline__ unsigned pk2bf(float a, float b) {
    unsigned short ua = __builtin_bit_cast(unsigned short, (__bf16)a);
    unsigned short ub = __builtin_bit_cast(unsigned short, (__bf16)b);
    return (unsigned)ua | ((unsigned)ub << 16);
}
__device__ __forceinline__ float bfhi(unsigned u) { return __builtin_bit_cast(float, u & 0xFFFF0000u); }
__device__ __forceinline__ float bflo(unsigned u) { return __builtin_bit_cast(float, u << 16); }

// device-scope (sc1) 16B load — coherent across XCDs, bypasses stale L1/L2
__device__ __forceinline__ u32x4 load16_sc1(const void* p) {
    u32x4 r;
    asm volatile("global_load_dwordx4 %0, %1, off sc1\n\t"
                 "s_waitcnt vmcnt(0)"
                 : "=v"(r) : "v"(p) : "memory");
    return r;
}

__global__ __launch_bounds__(256) void lstm_init(unsigned short* htA, unsigned* cnt, float* out) {
    int idx = blockIdx.x * 256 + threadIdx.x;          // 65536 threads
    uint4 z; z.x = 0; z.y = 0; z.z = 0; z.w = 0;
    ((uint4*)htA)[idx] = z;                            // zero 1 MB (ht(-1) = 0, frag order)
    if (idx < 512) cnt[idx] = 0;                       // 8 group counters (64-uint stride)
    if (idx < 5120) out[idx] = 0.05f;                  // sentinel, overwritten by lstm_main
}

__global__ __attribute__((amdgpu_flat_work_group_size(256, 256), amdgpu_waves_per_eu(1, 1)))
void lstm_main(
    const float* __restrict__ x,
    const float* __restrict__ Wgx, const float* __restrict__ Wgh, const float* __restrict__ bg,
    const float* __restrict__ Wix, const float* __restrict__ Wih, const float* __restrict__ bi,
    const float* __restrict__ Wfx, const float* __restrict__ Wfh, const float* __restrict__ bf_,
    const float* __restrict__ Wox, const float* __restrict__ Woh, const float* __restrict__ bo,
    const float* __restrict__ Wph, const float* __restrict__ bp,
    float* __restrict__ out,
    unsigned short* __restrict__ htA, unsigned short* __restrict__ htB,
    unsigned* __restrict__ cnt)
{
    // B-fragment staging: [buf][kk_local(16)][nt(2)][lane(64)] of 16B -> 64 KiB
    __shared__ uint4 ldsB[2][16][2][64];

    const int tid = threadIdx.x;
    const int w   = tid >> 6;        // wave 0..3
    const int l   = tid & 63;
    const int l31 = l & 31;
    const int h5  = l >> 5;
    const int gid = blockIdx.x;
    const int c   = gid & 7;         // batch group (64 batches)
    const int r   = gid >> 3;        // h group (32 h)

    // ---- load A fragments (weights, bf16) into registers: 64 k-steps x bf16x8 ----
    // A row m = l31: gate = m>>3, dh = m&7 ; within one MFMA, k = h5*8 + e
    const int gate = l31 >> 3;
    const int hrow = (r << 5) + (w << 3) + (l & 7);
    const float* Wsel = (gate == 0) ? Wgh : (gate == 1) ? Wih : (gate == 2) ? Wfh : Woh;
    const float* wrow = Wsel + hrow * HID + (h5 << 3);
    bf16x8 A[64];
#pragma unroll
    for (int kk = 0; kk < 64; ++kk) {
        const float4* p = (const float4*)(wrow + kk * 16);
        float4 u0 = p[0], u1 = p[1];
        bf16x8 a;
        a[0] = (__bf16)u0.x; a[1] = (__bf16)u0.y; a[2] = (__bf16)u0.z; a[3] = (__bf16)u0.w;
        a[4] = (__bf16)u1.x; a[5] = (__bf16)u1.y; a[6] = (__bf16)u1.z; a[7] = (__bf16)u1.w;
        A[kk] = a;
        __builtin_amdgcn_sched_barrier(0);   // bound register pressure during init
    }

    // ---- per-lane Wx / bias for the 16 accumulator rows ----
    // acc reg j -> D row = (j&3) + 8*(j>>2) + 4*h5  => gate=j>>2, dh=(j&3)+4*h5
    float wx16[16], bs16[16];
    {
        const float* WxA[4] = {Wgx, Wix, Wfx, Wox};
        const float* bA[4]  = {bg, bi, bf_, bo};
#pragma unroll
        for (int j = 0; j < 16; ++j) {
            int g = j >> 2;
            int h = (r << 5) + (w << 3) + (j & 3) + (h5 << 2);
            wx16[j] = WxA[g][h];
            bs16[j] = bA[g][h];
        }
    }

    float ct[8];
#pragma unroll
    for (int i = 0; i < 8; ++i) ct[i] = 0.f;

    const unsigned short* htR = htA;   // ht(t-1), fragment order
    unsigned short*       htW = htB;   // ht(t)
    unsigned* mycnt = cnt + (c << 6);

    for (int t = 0; t < SEQL; ++t) {
        // per-step input values (b = 64c + nt*32 + l31)
        float xv0 = x[(unsigned)((c << 6) + l31) * SEQL + (unsigned)t];
        float xv1 = x[(unsigned)((c << 6) + 32 + l31) * SEQL + (unsigned)t];

        const unsigned short* gR = htR + (c << 16);   // this group's 128 KiB region

        // stage chunk 0 (each wave: 8 x global_load_lds of 1 KiB, device-scope sc1)
#pragma unroll
        for (int j = 0; j < 8; ++j) {
            int q = (w << 3) + j;                      // pair id = kk_local*2 + nt
            const void* g = (const void*)(gR + q * 512 + (l << 3));
            __builtin_amdgcn_global_load_lds((const AS1 void*)g,
                (AS3 void*)&ldsB[0][q >> 1][q & 1][0], 16, 0, 0x10 /*sc1*/);
        }

        // init accumulators with bias + Wx*x_t
        f32x16 acc0, acc1;
#pragma unroll
        for (int j = 0; j < 16; ++j) {
            acc0[j] = fmaf(wx16[j], xv0, bs16[j]);
            acc1[j] = fmaf(wx16[j], xv1, bs16[j]);
        }

        // ---- K loop: 4 chunks x 16 k-steps, double-buffered staging ----
#pragma unroll
        for (int ch = 0; ch < 4; ++ch) {
            if (ch < 3) {
#pragma unroll
                for (int j = 0; j < 8; ++j) {
                    int q = (w << 3) + j;
                    const void* g = (const void*)(gR + (ch + 1) * 16384 + q * 512 + (l << 3));
                    __builtin_amdgcn_global_load_lds((const AS1 void*)g,
                        (AS3 void*)&ldsB[(ch + 1) & 1][q >> 1][q & 1][0], 16, 0, 0x10 /*sc1*/);
                }
                // per-wave: ch's 8 loads done, ch+1's 8 may stay in flight
                asm volatile("s_waitcnt vmcnt(8)" ::: "memory");
            } else {
                asm volatile("s_waitcnt vmcnt(0)" ::: "memory");
            }
            __builtin_amdgcn_s_barrier();
            asm volatile("" ::: "memory");
#pragma unroll
            for (int kk = 0; kk < 16; ++kk) {
                bf16x8 b0 = __builtin_bit_cast(bf16x8, ldsB[ch & 1][kk][0][l]);
                bf16x8 b1 = __builtin_bit_cast(bf16x8, ldsB[ch & 1][kk][1][l]);
                acc0 = __builtin_amdgcn_mfma_f32_32x32x16_bf16(A[ch * 16 + kk], b0, acc0, 0, 0, 0);
                acc1 = __builtin_amdgcn_mfma_f32_32x32x16_bf16(A[ch * 16 + kk], b1, acc1, 0, 0, 0);
            }
            asm volatile("" ::: "memory");
            __builtin_amdgcn_s_barrier();
        }

        // ---- activations + state update (all 4 gates live in this lane) ----
        float htv[8];
#pragma unroll
        for (int nt = 0; nt < 2; ++nt) {
            f32x16 ac = nt ? acc1 : acc0;
#pragma unroll
            for (int d = 0; d < 4; ++d) {
                float g  = fast_tanh(ac[d]);
                float ii = fast_sigmoid(ac[4 + d]);
                float ff = fast_sigmoid(ac[8 + d]);
                float oo = fast_sigmoid(ac[12 + d]);
                float cc = fmaf(ct[nt * 4 + d], ff, g * ii);
                ct[nt * 4 + d] = cc;
                htv[nt * 4 + d] = fast_tanh(cc) * oo;
            }
        }

        // ---- store ht(t) as bf16, B-fragment order, device-scope write-through (sc1) ----
        {
            unsigned short* gW = htW + (c << 16);
            int kkw  = (r << 1) + (w >> 1);
            int slot = ((w & 1) << 5) + l31;
#pragma unroll
            for (int nt = 0; nt < 2; ++nt) {
                unsigned lo = pk2bf(htv[nt * 4 + 0], htv[nt * 4 + 1]);
                unsigned hi = pk2bf(htv[nt * 4 + 2], htv[nt * 4 + 3]);
                unsigned long long v = (unsigned long long)lo | ((unsigned long long)hi << 32);
                unsigned long long* dst =
                    (unsigned long long*)(gW + (((kkw * 2 + nt) * 64 + slot) * 8 + (h5 << 2)));
                __hip_atomic_store(dst, v, __ATOMIC_RELAXED, __HIP_MEMORY_SCOPE_AGENT);
            }
        }

        // ---- group barrier (32 wgs sharing this batch group) ----
        // __syncthreads(): every wave drains vmcnt(0) before arriving => all sc1 stores acked.
        __syncthreads();
        if (tid == 0) {
            __hip_atomic_fetch_add(mycnt, 1u, __ATOMIC_RELAXED, __HIP_MEMORY_SCOPE_AGENT);
            unsigned tgt = 32u * (unsigned)(t + 1);
            while (__hip_atomic_load(mycnt, __ATOMIC_RELAXED, __HIP_MEMORY_SCOPE_AGENT) < tgt) {
                __builtin_amdgcn_s_sleep(1);
            }
        }
        __syncthreads();

        const unsigned short* tmp = htR; htR = htW; htW = (unsigned short*)tmp;
    }

    // ---- final projection: out[b][cls] = Wph[cls,:] . ht[:,b] + bp[cls] ----
    // ht read from the bf16 fragment-order buffer with sc1 (device-coherent):
    //   elem(h, b) at region c*65536 + (h>>4)*1024 + ((b>>5)&1)*512 + ((h>>3)&1)*256 + (b&31)*8 + (h&7)
    // Lane l covers h in [16l, 16l+16): two 16B loads at +0 and +256 elems.
    {
        const unsigned short* hfin = htR + (c << 16);
        for (int p = w; p < 20; p += 4) {
            int bloc = (r << 1) + (p / 10);            // in-group batch 0..63
            int bb   = (c << 6) + bloc;
            int cls  = p % 10;
            const unsigned short* base = hfin + l * 1024 + ((bloc >> 5) & 1) * 512
                                              + (bloc & 31) * 8;
            u32x4 u0 = load16_sc1(base);               // h = 16l + 0..7
            u32x4 u1 = load16_sc1(base + 256);         // h = 16l + 8..15
            const float* wp = Wph + (unsigned)cls * HID + (unsigned)l * 16;
            float s = 0.f;
#pragma unroll
            for (int e = 0; e < 4; ++e) {
                s = fmaf(wp[2 * e],         bflo(u0[e]), s);
                s = fmaf(wp[2 * e + 1],     bfhi(u0[e]), s);
                s = fmaf(wp[8 + 2 * e],     bflo(u1[e]), s);
                s = fmaf(wp[8 + 2 * e + 1], bfhi(u1[e]), s);
            }
#pragma unroll
            for (int off = 32; off > 0; off >>= 1) s += __shfl_xor(s, off, 64);
            if (l == 0) out[bb * 10 + cls] = s + bp[cls];
        }
    }
}

extern "C" void kernel_launch(void* const* d_in, const int* in_sizes, int n_in,
                              void* d_out, int out_size, void* d_ws, size_t ws_size,
                              hipStream_t stream) {
    const float* x   = (const float*)d_in[0];
    const float* Wgx = (const float*)d_in[1];
    const float* Wgh = (const float*)d_in[2];
    const float* bg  = (const float*)d_in[3];
    const float* Wix = (const float*)d_in[4];
    const float* Wih = (const float*)d_in[5];
    const float* bi  = (const float*)d_in[6];
    const float* Wfx = (const float*)d_in[7];
    const float* Wfh = (const float*)d_in[8];
    const float* bf_ = (const float*)d_in[9];
    const float* Wox = (const float*)d_in[10];
    const float* Woh = (const float*)d_in[11];
    const float* bo  = (const float*)d_in[12];
    const float* Wph = (const float*)d_in[13];
    const float* bp  = (const float*)d_in[14];
    float* out = (float*)d_out;

    char* ws = (char*)d_ws;
    unsigned short* htA = (unsigned short*)ws;                 // 1 MiB, ht buffer A (frag order)
    unsigned short* htB = (unsigned short*)(ws + (1 << 20));   // 1 MiB, ht buffer B
    unsigned*       cnt = (unsigned*)(ws + (2 << 20));         // 2 KiB, group counters

    lstm_init<<<dim3(256), dim3(256), 0, stream>>>(htA, cnt, out);

    lstm_main<<<dim3(256), dim3(256), 0, stream>>>(
        x, Wgx, Wgh, bg, Wix, Wih, bi, Wfx, Wfh, bf_,
        Wox, Woh, bo, Wph, bp, out, htA, htB, cnt);
}